// Round 3
// baseline (5075.576 us; speedup 1.0000x reference)
//
#include <hip/hip_runtime.h>
#include <cstdint>

// ODEModel: y0 = mean_T(x0[B,200,6]); 101 RK4 steps of 6->50->50->6 ReLU MLP.
// One thread per batch element (lane = batch).
//
// R2: weights/biases/t_span live in __constant__ symbols (copied in
// kernel_launch via hipMemcpyToSymbolAsync, D2D, graph-capture safe).
// File-scope __constant__ + uniform index == guaranteed scalar loads
// (s_load_dwordx16) -> every FMA is v_fmac_f32 v,s,v with ZERO address VALU.
// R0/R1 lesson: pointer-based weight reads compiled to per-lane flat loads
// (3 addr-VALU per load -> 13.1K VALU instrs/eval vs 3.3K floor -> 4780us).

#define D_IN   6
#define H_DIM  50
#define T_LEN  200
#define NT_MAX 128

__constant__ float cW1[D_IN * H_DIM];    // 300
__constant__ float cb1[H_DIM];           // 50
__constant__ float cW2[H_DIM * H_DIM];   // 2500
__constant__ float cb2[H_DIM];           // 50
__constant__ float cW3[H_DIM * D_IN];    // 300
__constant__ float cb3[D_IN];            // 6
__constant__ float cts[NT_MAX];          // 102 used

__device__ __forceinline__ void mlp_eval(const float y[D_IN], float k[D_IN])
{
    // layer 1: 6 -> 50, ReLU
    float h1[H_DIM];
#pragma unroll
    for (int j = 0; j < H_DIM; ++j) h1[j] = cb1[j];
#pragma unroll
    for (int i = 0; i < D_IN; ++i) {
        float v = y[i];
#pragma unroll
        for (int j = 0; j < H_DIM; ++j) h1[j] = fmaf(v, cW1[i * H_DIM + j], h1[j]);
    }
#pragma unroll
    for (int j = 0; j < H_DIM; ++j) h1[j] = fmaxf(h1[j], 0.0f);

    // layer 2: 50 -> 50 (ReLU applied at consumption in layer 3)
    float h2[H_DIM];
#pragma unroll
    for (int j = 0; j < H_DIM; ++j) h2[j] = cb2[j];
#pragma unroll
    for (int i = 0; i < H_DIM; ++i) {
        float v = h1[i];
#pragma unroll
        for (int j = 0; j < H_DIM; ++j) h2[j] = fmaf(v, cW2[i * H_DIM + j], h2[j]);
    }

    // layer 3: 50 -> 6
#pragma unroll
    for (int d = 0; d < D_IN; ++d) k[d] = cb3[d];
#pragma unroll
    for (int i = 0; i < H_DIM; ++i) {
        float v = fmaxf(h2[i], 0.0f);
#pragma unroll
        for (int d = 0; d < D_IN; ++d) k[d] = fmaf(v, cW3[i * D_IN + d], k[d]);
    }
}

extern "C" __global__ __launch_bounds__(256)
void ode_fused(const float* __restrict__ x0, float* __restrict__ out, int nt)
{
    // No bounds check: grid*block == B exactly (B = 65536) -> uniform control
    // flow, scalar loads legal everywhere.
    int b = blockIdx.x * blockDim.x + threadIdx.x;

    // ---- phase 1: y0 = mean over T of x0[b, :, :] (1200 contiguous floats) ----
    const float4* xrow = (const float4*)(x0 + (size_t)b * (T_LEN * D_IN));
    float acc[D_IN];
#pragma unroll
    for (int d = 0; d < D_IN; ++d) acc[d] = 0.0f;

#pragma unroll 4
    for (int c = 0; c < (T_LEN * D_IN) / 12; ++c) {
        float4 v0 = xrow[c * 3 + 0];
        float4 v1 = xrow[c * 3 + 1];
        float4 v2 = xrow[c * 3 + 2];
        acc[0] += v0.x + v1.z;
        acc[1] += v0.y + v1.w;
        acc[2] += v0.z + v2.x;
        acc[3] += v0.w + v2.y;
        acc[4] += v1.x + v2.z;
        acc[5] += v1.y + v2.w;
    }

    float y[D_IN];
#pragma unroll
    for (int d = 0; d < D_IN; ++d) y[d] = acc[d] * (1.0f / (float)T_LEN);

    // ---- phase 2: RK4 over nt-1 steps ----
#pragma unroll 1
    for (int s = 0; s < nt - 1; ++s) {
        float dt = cts[s + 1] - cts[s];

        float acck[D_IN];
        float yt[D_IN];
#pragma unroll
        for (int d = 0; d < D_IN; ++d) { acck[d] = 0.0f; yt[d] = y[d]; }

#pragma unroll 1
        for (int st = 0; st < 4; ++st) {
            float k[D_IN];
            mlp_eval(yt, k);
            float w = (st == 1 || st == 2) ? 2.0f : 1.0f;  // k weights 1,2,2,1
            float a = (st == 2) ? 1.0f : 0.5f;             // y-offset coeff
#pragma unroll
            for (int d = 0; d < D_IN; ++d) {
                acck[d] = fmaf(w, k[d], acck[d]);
                yt[d]   = fmaf(a * dt, k[d], y[d]);
            }
        }
#pragma unroll
        for (int d = 0; d < D_IN; ++d) y[d] = fmaf(dt * (1.0f / 6.0f), acck[d], y[d]);
    }

    // ---- write y[-1] ----
    float* o = out + (size_t)b * D_IN;
#pragma unroll
    for (int d = 0; d < D_IN; ++d) o[d] = y[d];
}

extern "C" void kernel_launch(void* const* d_in, const int* in_sizes, int n_in,
                              void* d_out, int out_size, void* d_ws, size_t ws_size,
                              hipStream_t stream) {
    const float* x0 = (const float*)d_in[0];
    float* out = (float*)d_out;

    int B  = in_sizes[0] / (T_LEN * D_IN);
    int nt = in_sizes[1];

    // Stage params into __constant__ symbols (device-to-device, stream-ordered;
    // replayed inside the graph on every launch).
    hipMemcpyToSymbolAsync(HIP_SYMBOL(cts), d_in[1], in_sizes[1] * sizeof(float), 0,
                           hipMemcpyDeviceToDevice, stream);
    hipMemcpyToSymbolAsync(HIP_SYMBOL(cW1), d_in[2], in_sizes[2] * sizeof(float), 0,
                           hipMemcpyDeviceToDevice, stream);
    hipMemcpyToSymbolAsync(HIP_SYMBOL(cb1), d_in[3], in_sizes[3] * sizeof(float), 0,
                           hipMemcpyDeviceToDevice, stream);
    hipMemcpyToSymbolAsync(HIP_SYMBOL(cW2), d_in[4], in_sizes[4] * sizeof(float), 0,
                           hipMemcpyDeviceToDevice, stream);
    hipMemcpyToSymbolAsync(HIP_SYMBOL(cb2), d_in[5], in_sizes[5] * sizeof(float), 0,
                           hipMemcpyDeviceToDevice, stream);
    hipMemcpyToSymbolAsync(HIP_SYMBOL(cW3), d_in[6], in_sizes[6] * sizeof(float), 0,
                           hipMemcpyDeviceToDevice, stream);
    hipMemcpyToSymbolAsync(HIP_SYMBOL(cb3), d_in[7], in_sizes[7] * sizeof(float), 0,
                           hipMemcpyDeviceToDevice, stream);

    dim3 block(256);
    dim3 grid(B / 256);  // B = 65536, exact multiple -- no tail
    hipLaunchKernelGGL(ode_fused, grid, block, 0, stream, x0, out, nt);
}